// Round 1
// baseline (1057.362 us; speedup 1.0000x reference)
//
#include <hip/hip_runtime.h>
#include <hip/hip_bf16.h>
#include <cstdint>
#include <cstddef>

typedef unsigned short u16;
typedef unsigned int   u32;
typedef unsigned char  u8;

#define NCLS 41

typedef short s16x8 __attribute__((ext_vector_type(8)));
typedef float f32x4 __attribute__((ext_vector_type(4)));

__device__ __forceinline__ u16 f2bf(float f) {          // RNE float->bf16
  u32 u = __float_as_uint(f);
  u += 0x7fffu + ((u >> 16) & 1u);
  return (u16)(u >> 16);
}

// ---- async global->LDS (16B/lane, wave-uniform LDS base) ------------------
#if __has_builtin(__builtin_amdgcn_global_load_lds)
#define HAVE_GLL 1
typedef const __attribute__((address_space(1))) u32* gas1p;
typedef __attribute__((address_space(3))) u32* las3p;
__device__ __forceinline__ void gll16(const void* g, void* l) {
  __builtin_amdgcn_global_load_lds((gas1p)g, (las3p)l, 16, 0, 0);
}
#else
#define HAVE_GLL 0
#endif

// ===========================================================================
// K_w: w_fuse [128oc][256ic][3][3] f32  ->  Wt [9tap][128oc][256ic] bf16
// ===========================================================================
__global__ void k_wprep(const float* __restrict__ wf, u16* __restrict__ Wt) {
  const int e = blockIdx.x * 256 + threadIdx.x;
  if (e >= 9 * 128 * 256) return;
  const int tap = e / (128 * 256);
  const int oc  = (e / 256) % 128;
  const int ic  = e % 256;
  Wt[e] = f2bf(wf[((size_t)oc * 256 + ic) * 9 + tap]);
}

// ===========================================================================
// K1: build X = padded-NHWC bf16 [4][226][226][256]; ic 0-127 = r+d,
//     ic 128-255 = r*sigmoid(d).  Halo rows/cols zeroed.  Block = (b, yp).
// ===========================================================================
__global__ __launch_bounds__(256) void k_prep(const float* __restrict__ r,
                                              const float* __restrict__ d,
                                              u16* __restrict__ X) {
  const int t  = threadIdx.x;
  const int yp = blockIdx.x % 226;
  const int b  = blockIdx.x / 226;
  u32* Xrow = (u32*)(X + (size_t)(b * 226 + yp) * 226 * 256);  // 226 px * 128 u32
  if (yp == 0 || yp == 225) {
    for (int e = t; e < 226 * 128; e += 256) Xrow[e] = 0u;
    return;
  }
  const int y = yp - 1;
  if (t < 128) Xrow[t] = 0u;                       // x halo (padded col 0)
  else         Xrow[225 * 128 + (t - 128)] = 0u;   // x halo (padded col 225)

  __shared__ float lA[16 * 225];
  __shared__ float lM[16 * 225];
  const float* rb = r + (size_t)b * 128 * 50176 + y * 224;
  const float* db = d + (size_t)b * 128 * 50176 + y * 224;
  for (int c0 = 0; c0 < 128; c0 += 16) {
    __syncthreads();
    for (int e = t; e < 16 * 224; e += 256) {      // coalesced along x
      const int c = e / 224, x = e % 224;
      const float rv = rb[(size_t)(c0 + c) * 50176 + x];
      const float dv = db[(size_t)(c0 + c) * 50176 + x];
      lA[c * 225 + x] = rv + dv;
      lM[c * 225 + x] = rv / (1.f + __expf(-dv));
    }
    __syncthreads();
    for (int e = t; e < 224 * 8; e += 256) {       // pack 2 bf16 per u32
      const int px = e / 8, j = e % 8, cj = 2 * j;
      u32 a0 = (u32)f2bf(lA[cj * 225 + px]) | ((u32)f2bf(lA[(cj + 1) * 225 + px]) << 16);
      u32 m0 = (u32)f2bf(lM[cj * 225 + px]) | ((u32)f2bf(lM[(cj + 1) * 225 + px]) << 16);
      Xrow[(px + 1) * 128 +      (c0 >> 1) + j] = a0;
      Xrow[(px + 1) * 128 + 64 + (c0 >> 1) + j] = m0;
    }
  }
}

// ===========================================================================
// K2: labels_ds (::4,::4) -> u8 [4][224][224]; histogram -> counts[4*41]
// ===========================================================================
__global__ void k_labels(const int* __restrict__ label, u8* __restrict__ labs,
                         int* __restrict__ counts) {
  const int i = blockIdx.x % 224, b = blockIdx.x / 224;
  __shared__ int hist[NCLS];
  const int t = threadIdx.x;
  if (t < NCLS) hist[t] = 0;
  __syncthreads();
  if (t < 224) {
    const int v = label[((size_t)b * 896 + 4 * i) * 896 + 4 * t];
    labs[((size_t)b * 224 + i) * 224 + t] = (u8)v;
    atomicAdd(&hist[v], 1);
  }
  __syncthreads();
  if (t < NCLS) atomicAdd(&counts[b * NCLS + t], hist[t]);
}

// ===========================================================================
// K3: segment-sum of d (NCHW f32) -> partials [b][56][41][128]
//     Block = (b, 4-row group). LDS acc stride 129 spreads banks.
// ===========================================================================
__global__ __launch_bounds__(256) void k_segd(const float* __restrict__ d,
                                              const u8* __restrict__ labs,
                                              float* __restrict__ part) {
  const int p = blockIdx.x % 56, b = blockIdx.x / 56;
  const int y0 = p * 4;
  __shared__ float acc[NCLS * 129];
  __shared__ u8 ll[4 * 224];
  const int t = threadIdx.x;
  for (int e = t; e < NCLS * 129; e += 256) acc[e] = 0.f;
  for (int e = t; e < 4 * 224; e += 256) ll[e] = labs[((size_t)b * 224 + y0) * 224 + e];
  __syncthreads();
  const float* db = d + (size_t)b * 128 * 50176;
  for (int e = t; e < 4 * 128 * 224; e += 256) {
    const int x = e % 224, c = (e / 224) % 128, rr = e / (224 * 128);
    const float v = db[(size_t)c * 50176 + (y0 + rr) * 224 + x];
    atomicAdd(&acc[(int)ll[rr * 224 + x] * 129 + c], v);
  }
  __syncthreads();
  float* pb = part + (size_t)(b * 56 + p) * NCLS * 128;
  for (int e = t; e < NCLS * 128; e += 256) pb[e] = acc[(e / 128) * 129 + (e % 128)];
}

// ===========================================================================
// K4: conv3x3 as implicit GEMM, bf16 MFMA 16x16x32 (m97 structure).
//     Block: 256 thr / 4 waves, tile 128 pos x 128 oc, K-loop 9 taps x 8
//     slices of 32.  A = X (NHWC, padded), B = Wt [tap][oc][ic].
//     Output fuse = NHWC bf16 [4][224][224][128].
// ===========================================================================
__global__ __launch_bounds__(256) void k_conv(const u16* __restrict__ X,
                                              const u16* __restrict__ Wt,
                                              u16* __restrict__ fuse) {
  __shared__ u16 Alds[128 * 32];
  __shared__ u16 Blds[128 * 32];
  const int t = threadIdx.x;
  const int w = t >> 6, l = t & 63;
  const int lrow = l & 15, lq = l >> 4;
  const int wm = (w & 1) * 64, wn = (w >> 1) * 64;
  const int x0 = blockIdx.x * 128;
  const int y  = blockIdx.y;
  const int b  = blockIdx.z;

  f32x4 acc[4][4] = {};

  const int posA = t >> 2;          // staging: lane covers (pos, 8-ch chunk)
  const int koff = (t & 3) * 8;
  char* ldsA0 = (char*)Alds + (w * 64) * 16;   // wave-uniform LDS bases
  char* ldsB0 = (char*)Blds + (w * 64) * 16;

  for (int tap = 0; tap < 9; ++tap) {
    const int dy = tap / 3, dx = tap % 3;
    const u16* Abase = X + ((size_t)((b * 226 + y + dy) * 226) + (x0 + dx)) * 256;
    const u16* Bbase = Wt + (size_t)tap * (128 * 256);
    for (int s = 0; s < 8; ++s) {
      const int kb = s * 32;
      const u16* ga0 = Abase + (size_t)posA * 256 + kb + koff;
      const u16* gb0 = Bbase + (size_t)posA * 256 + kb + koff;
#if HAVE_GLL
      gll16(ga0, ldsA0);
      gll16(gb0, ldsB0);
      gll16(ga0 + 64 * 256, ldsA0 + 256 * 16);
      gll16(gb0 + 64 * 256, ldsB0 + 256 * 16);
#else
      *(uint4*)((char*)Alds + (size_t)t * 16)         = *(const uint4*)ga0;
      *(uint4*)((char*)Blds + (size_t)t * 16)         = *(const uint4*)gb0;
      *(uint4*)((char*)Alds + (size_t)(256 + t) * 16) = *(const uint4*)(ga0 + 64 * 256);
      *(uint4*)((char*)Blds + (size_t)(256 + t) * 16) = *(const uint4*)(gb0 + 64 * 256);
#endif
      __syncthreads();
      s16x8 af[4], bfr[4];
#pragma unroll
      for (int mi = 0; mi < 4; ++mi)
        af[mi] = *(const s16x8*)((const char*)Alds + (wm + mi * 16 + lrow) * 64 + lq * 16);
#pragma unroll
      for (int ni = 0; ni < 4; ++ni)
        bfr[ni] = *(const s16x8*)((const char*)Blds + (wn + ni * 16 + lrow) * 64 + lq * 16);
#pragma unroll
      for (int mi = 0; mi < 4; ++mi)
#pragma unroll
        for (int ni = 0; ni < 4; ++ni)
          acc[mi][ni] = __builtin_amdgcn_mfma_f32_16x16x32_bf16(af[mi], bfr[ni], acc[mi][ni], 0, 0, 0);
      __syncthreads();
    }
  }
  // epilogue: D row = pos (C/D layout row = lq*4+reg), col = oc (l&15)
#pragma unroll
  for (int mi = 0; mi < 4; ++mi) {
#pragma unroll
    for (int rr = 0; rr < 4; ++rr) {
      const int pos = wm + mi * 16 + lq * 4 + rr;
      const int x = x0 + pos;
      if (x < 224) {
        u16* dst = fuse + ((size_t)(b * 224 + y) * 224 + x) * 128;
#pragma unroll
        for (int ni = 0; ni < 4; ++ni) {
          const int oc = wn + ni * 16 + lrow;
          dst[oc] = f2bf(acc[mi][ni][rr]);
        }
      }
    }
  }
}

// ===========================================================================
// K5: segment-sum of fuse (NHWC bf16) -> partials [b][56][41][128]
// ===========================================================================
__global__ __launch_bounds__(256) void k_segf(const u16* __restrict__ fuse,
                                              const u8* __restrict__ labs,
                                              float* __restrict__ part) {
  const int p = blockIdx.x % 56, b = blockIdx.x / 56;
  const int y0 = p * 4;
  __shared__ float acc[NCLS * 129];
  __shared__ u8 ll[4 * 224];
  const int t = threadIdx.x;
  for (int e = t; e < NCLS * 129; e += 256) acc[e] = 0.f;
  for (int e = t; e < 4 * 224; e += 256) ll[e] = labs[((size_t)b * 224 + y0) * 224 + e];
  __syncthreads();
  const u32* fb = (const u32*)(fuse + ((size_t)b * 224 + y0) * 224 * 128);
  for (int e = t; e < 4 * 224 * 64; e += 256) {
    const int c2 = e % 64, px = e / 64;
    const u32 v = fb[(size_t)px * 64 + c2];
    const int lab = ll[px];
    atomicAdd(&acc[lab * 129 + 2 * c2],     __uint_as_float(v << 16));
    atomicAdd(&acc[lab * 129 + 2 * c2 + 1], __uint_as_float(v & 0xffff0000u));
  }
  __syncthreads();
  float* pb = part + (size_t)(b * 56 + p) * NCLS * 128;
  for (int e = t; e < NCLS * 128; e += 256) pb[e] = acc[(e / 128) * 129 + (e % 128)];
}

// ===========================================================================
// K6: gates.  One block per batch.  sums -> mean -> att (per-channel norm
//     across classes) -> relu MLP -> sigmoid.  gates[b*128+c]
// ===========================================================================
__global__ __launch_bounds__(256) void k_gates(const float* __restrict__ part,
                                               const int* __restrict__ counts,
                                               const float* __restrict__ w1,
                                               const float* __restrict__ w2,
                                               float* __restrict__ gates) {
  const int b = blockIdx.x;
  __shared__ float sums[NCLS * 128];
  __shared__ float att[128];
  __shared__ float hid[8];
  const int t = threadIdx.x;
  for (int e = t; e < NCLS * 128; e += 256) {
    float s = 0.f;
    const float* pp = part + (size_t)b * 56 * NCLS * 128 + e;
    for (int p = 0; p < 56; ++p) s += pp[(size_t)p * NCLS * 128];
    sums[e] = s;
  }
  __syncthreads();
  if (t < 128) {
    float s1 = 0.f, s2 = 0.f;
    for (int lb = 0; lb < NCLS; ++lb) {
      const float cnt = (float)counts[b * NCLS + lb];
      const float m = sums[lb * 128 + t] / fmaxf(cnt, 1.f);
      s1 += m; s2 += m * m;
    }
    att[t] = s1 / fmaxf(sqrtf(s2), 1e-12f);
  }
  __syncthreads();
  if (t < 8) {
    float h = 0.f;
    for (int c = 0; c < 128; ++c) h += att[c] * w1[t * 128 + c];
    hid[t] = fmaxf(h, 0.f);
  }
  __syncthreads();
  if (t < 128) {
    float o = 0.f;
    for (int j = 0; j < 8; ++j) o += hid[j] * w2[t * 8 + j];
    gates[b * 128 + t] = 1.f / (1.f + expf(-o));
  }
}

// ===========================================================================
// K7: out(NCHW f32) = fuse(NHWC bf16)*gate_f + d(NCHW)*gate_d
//     Block = (b,y); LDS transpose of fuse row back to channel-major.
// ===========================================================================
__global__ __launch_bounds__(256) void k_out(const u16* __restrict__ fuse,
                                             const float* __restrict__ d,
                                             const float* __restrict__ gates,
                                             float* __restrict__ out) {
  const int y = blockIdx.x % 224, b = blockIdx.x / 224;
  __shared__ float flds[224 * 33];
  __shared__ float gf[128], gd[128];
  const int t = threadIdx.x;
  if (t < 128) gd[t] = gates[b * 128 + t];
  else         gf[t - 128] = gates[512 + b * 128 + (t - 128)];
  const u32* frow = (const u32*)fuse + ((size_t)b * 224 + y) * 224 * 64;
  const float* db = d + (size_t)b * 128 * 50176 + y * 224;
  float* ob = out + (size_t)b * 128 * 50176 + y * 224;
  for (int c0 = 0; c0 < 128; c0 += 32) {
    __syncthreads();
    for (int e = t; e < 224 * 16; e += 256) {
      const int px = e / 16, q = e % 16;
      const u32 v = frow[(size_t)px * 64 + (c0 >> 1) + q];
      flds[px * 33 + 2 * q]     = __uint_as_float(v << 16);
      flds[px * 33 + 2 * q + 1] = __uint_as_float(v & 0xffff0000u);
    }
    __syncthreads();
    for (int e = t; e < 32 * 224; e += 256) {
      const int cc = e / 224, x = e % 224, c = c0 + cc;
      ob[(size_t)c * 50176 + x] = flds[x * 33 + cc] * gf[c] + db[(size_t)c * 50176 + x] * gd[c];
    }
  }
}

// ===========================================================================
extern "C" void kernel_launch(void* const* d_in, const int* in_sizes, int n_in,
                              void* d_out, int out_size, void* d_ws, size_t ws_size,
                              hipStream_t stream) {
  const float* r     = (const float*)d_in[0];
  const float* d     = (const float*)d_in[1];
  const int*   label = (const int*)d_in[2];
  const float* wf    = (const float*)d_in[3];
  const float* w1d   = (const float*)d_in[4];
  const float* w2d   = (const float*)d_in[5];
  const float* w1f   = (const float*)d_in[6];
  const float* w2f   = (const float*)d_in[7];
  float* out = (float*)d_out;

  char* ws = (char*)d_ws;
  size_t off = 0;
  auto carve = [&](size_t bytes) -> char* {
    char* p = ws + off;
    off = (off + bytes + 511) & ~(size_t)511;
    return p;
  };
  u16* X       = (u16*)carve((size_t)4 * 226 * 226 * 256 * 2 + 65536);  // padded NHWC + OOB pad
  u16* Wt      = (u16*)carve((size_t)9 * 128 * 256 * 2);
  u16* fuseb   = (u16*)carve((size_t)4 * 224 * 224 * 128 * 2);
  u8*  labs    = (u8*) carve((size_t)4 * 224 * 224);
  int* counts  = (int*)carve(4 * NCLS * sizeof(int));
  float* partd = (float*)carve((size_t)4 * 56 * NCLS * 128 * 4);
  float* partf = (float*)carve((size_t)4 * 56 * NCLS * 128 * 4);
  float* gates = (float*)carve(1024 * sizeof(float));

  hipMemsetAsync(counts, 0, 4 * NCLS * sizeof(int), stream);
  k_wprep <<<(9 * 128 * 256 + 255) / 256, 256, 0, stream>>>(wf, Wt);
  k_prep  <<<4 * 226, 256, 0, stream>>>(r, d, X);
  k_labels<<<4 * 224, 256, 0, stream>>>(label, labs, counts);
  k_segd  <<<4 * 56, 256, 0, stream>>>(d, labs, partd);
  k_conv  <<<dim3(2, 224, 4), 256, 0, stream>>>(X, Wt, fuseb);
  k_segf  <<<4 * 56, 256, 0, stream>>>(fuseb, labs, partf);
  k_gates <<<4, 256, 0, stream>>>(partd, counts, w1d, w2d, gates);        // gates[0..511]   = d-module
  k_gates <<<4, 256, 0, stream>>>(partf, counts, w1f, w2f, gates + 512);  // gates[512..1023]= fuse-module
  k_out   <<<4 * 224, 256, 0, stream>>>(fuseb, d, gates, out);
}

// Round 2
// 868.562 us; speedup vs baseline: 1.2174x; 1.2174x over previous
//
#include <hip/hip_runtime.h>
#include <hip/hip_bf16.h>
#include <cstdint>
#include <cstddef>

typedef unsigned short u16;
typedef unsigned int   u32;
typedef unsigned char  u8;

#define NCLS 41

typedef short s16x8 __attribute__((ext_vector_type(8)));
typedef float f32x4 __attribute__((ext_vector_type(4)));

__device__ __forceinline__ u16 f2bf(float f) {          // RNE float->bf16
  u32 u = __float_as_uint(f);
  u += 0x7fffu + ((u >> 16) & 1u);
  return (u16)(u >> 16);
}

// ---- async global->LDS (16B/lane, wave-uniform LDS base) ------------------
#if __has_builtin(__builtin_amdgcn_global_load_lds)
#define HAVE_GLL 1
typedef const __attribute__((address_space(1))) u32* gas1p;
typedef __attribute__((address_space(3))) u32* las3p;
__device__ __forceinline__ void gll16(const void* g, void* l) {
  __builtin_amdgcn_global_load_lds((gas1p)g, (las3p)l, 16, 0, 0);
}
#else
#define HAVE_GLL 0
#endif

// ===========================================================================
// K_w: w_fuse [128oc][256ic][3][3] f32  ->  Wt [9tap][128oc][256ic] bf16
// ===========================================================================
__global__ void k_wprep(const float* __restrict__ wf, u16* __restrict__ Wt) {
  const int e = blockIdx.x * 256 + threadIdx.x;
  if (e >= 9 * 128 * 256) return;
  const int tap = e / (128 * 256);
  const int oc  = (e / 256) % 128;
  const int ic  = e % 256;
  Wt[e] = f2bf(wf[((size_t)oc * 256 + ic) * 9 + tap]);
}

// ===========================================================================
// K2: labels_ds (::4,::4) -> u8 [4][224][224]; histogram -> counts[4*41]
// ===========================================================================
__global__ void k_labels(const int* __restrict__ label, u8* __restrict__ labs,
                         int* __restrict__ counts) {
  const int i = blockIdx.x % 224, b = blockIdx.x / 224;
  __shared__ int hist[NCLS];
  const int t = threadIdx.x;
  if (t < NCLS) hist[t] = 0;
  __syncthreads();
  if (t < 224) {
    const int v = label[((size_t)b * 896 + 4 * i) * 896 + 4 * t];
    labs[((size_t)b * 224 + i) * 224 + t] = (u8)v;
    atomicAdd(&hist[v], 1);
  }
  __syncthreads();
  if (t < NCLS) atomicAdd(&counts[b * NCLS + t], hist[t]);
}

// ===========================================================================
// K1: build X = padded-NHWC bf16 [4][226][226][256]; ic 0-127 = r+d,
//     ic 128-255 = r*sigmoid(d).  Halo rows/cols zeroed.  Block = (b, yp).
//     FUSED: segment-sum of d for this row -> global atomics into sums_d.
// ===========================================================================
__global__ __launch_bounds__(256) void k_prep(const float* __restrict__ r,
                                              const float* __restrict__ d,
                                              const u8* __restrict__ labs,
                                              u16* __restrict__ X,
                                              float* __restrict__ sums_d) {
  const int t  = threadIdx.x;
  const int yp = blockIdx.x % 226;
  const int b  = blockIdx.x / 226;
  u32* Xrow = (u32*)(X + (size_t)(b * 226 + yp) * 226 * 256);  // 226 px * 128 u32
  if (yp == 0 || yp == 225) {
    for (int e = t; e < 226 * 128; e += 256) Xrow[e] = 0u;
    return;
  }
  const int y = yp - 1;
  if (t < 128) Xrow[t] = 0u;                       // x halo (padded col 0)
  else         Xrow[225 * 128 + (t - 128)] = 0u;   // x halo (padded col 225)

  __shared__ float lA[16 * 225];
  __shared__ float lM[16 * 225];
  __shared__ float acc[NCLS * 129];                // seg-sum of d, pad 129
  __shared__ u8 ll[224];
  for (int e = t; e < NCLS * 129; e += 256) acc[e] = 0.f;
  if (t < 224) ll[t] = labs[((size_t)b * 224 + y) * 224 + t];

  const float* rb = r + (size_t)b * 128 * 50176 + y * 224;
  const float* db = d + (size_t)b * 128 * 50176 + y * 224;
  for (int c0 = 0; c0 < 128; c0 += 16) {
    __syncthreads();
    for (int e = t; e < 16 * 224; e += 256) {      // coalesced along x
      const int c = e / 224, x = e % 224;
      const float rv = rb[(size_t)(c0 + c) * 50176 + x];
      const float dv = db[(size_t)(c0 + c) * 50176 + x];
      lA[c * 225 + x] = rv + dv;
      lM[c * 225 + x] = rv / (1.f + __expf(-dv));
      atomicAdd(&acc[(int)ll[x] * 129 + (c0 + c)], dv);
    }
    __syncthreads();
    for (int e = t; e < 224 * 8; e += 256) {       // pack 2 bf16 per u32
      const int px = e / 8, j = e % 8, cj = 2 * j;
      u32 a0 = (u32)f2bf(lA[cj * 225 + px]) | ((u32)f2bf(lA[(cj + 1) * 225 + px]) << 16);
      u32 m0 = (u32)f2bf(lM[cj * 225 + px]) | ((u32)f2bf(lM[(cj + 1) * 225 + px]) << 16);
      Xrow[(px + 1) * 128 +      (c0 >> 1) + j] = a0;
      Xrow[(px + 1) * 128 + 64 + (c0 >> 1) + j] = m0;
    }
  }
  __syncthreads();                                  // acc complete
  for (int e = t; e < NCLS * 128; e += 256)
    atomicAdd(&sums_d[b * NCLS * 128 + e], acc[(e / 128) * 129 + (e % 128)]);
}

// ===========================================================================
// K4: conv3x3 as implicit GEMM, bf16 MFMA 16x16x32 (m97 structure).
//     Block: 256 thr / 4 waves, tile 128 pos x 128 oc, K-loop 9 taps x 8
//     slices of 32.  XCD-band swizzle: L%8 -> contiguous 28-row y band so
//     each XCD streams X rows through its private L2.
// ===========================================================================
__global__ __launch_bounds__(256) void k_conv(const u16* __restrict__ X,
                                              const u16* __restrict__ Wt,
                                              u16* __restrict__ fuse) {
  __shared__ u16 Alds[128 * 32];
  __shared__ u16 Blds[128 * 32];
  const int t = threadIdx.x;
  const int w = t >> 6, l = t & 63;
  const int lrow = l & 15, lq = l >> 4;
  const int wm = (w & 1) * 64, wn = (w >> 1) * 64;

  const int L   = blockIdx.x;        // 1792 blocks
  const int xcd = L & 7;             // heuristic: linear id % 8 = XCD
  const int i   = L >> 3;            // 0..223
  const int b   = i / 56;
  const int rem = i % 56;            // 28 y x 2 xtiles
  const int y   = xcd * 28 + (rem >> 1);
  const int x0  = (rem & 1) * 128;

  f32x4 acc[4][4] = {};

  const int posA = t >> 2;          // staging: lane covers (pos, 8-ch chunk)
  const int koff = (t & 3) * 8;
  char* ldsA0 = (char*)Alds + (w * 64) * 16;   // wave-uniform LDS bases
  char* ldsB0 = (char*)Blds + (w * 64) * 16;

  for (int tap = 0; tap < 9; ++tap) {
    const int dy = tap / 3, dx = tap % 3;
    const u16* Abase = X + ((size_t)((b * 226 + y + dy) * 226) + (x0 + dx)) * 256;
    const u16* Bbase = Wt + (size_t)tap * (128 * 256);
    for (int s = 0; s < 8; ++s) {
      const int kb = s * 32;
      const u16* ga0 = Abase + (size_t)posA * 256 + kb + koff;
      const u16* gb0 = Bbase + (size_t)posA * 256 + kb + koff;
#if HAVE_GLL
      gll16(ga0, ldsA0);
      gll16(gb0, ldsB0);
      gll16(ga0 + 64 * 256, ldsA0 + 256 * 16);
      gll16(gb0 + 64 * 256, ldsB0 + 256 * 16);
#else
      *(uint4*)((char*)Alds + (size_t)t * 16)         = *(const uint4*)ga0;
      *(uint4*)((char*)Blds + (size_t)t * 16)         = *(const uint4*)gb0;
      *(uint4*)((char*)Alds + (size_t)(256 + t) * 16) = *(const uint4*)(ga0 + 64 * 256);
      *(uint4*)((char*)Blds + (size_t)(256 + t) * 16) = *(const uint4*)(gb0 + 64 * 256);
#endif
      __syncthreads();
      s16x8 af[4], bfr[4];
#pragma unroll
      for (int mi = 0; mi < 4; ++mi)
        af[mi] = *(const s16x8*)((const char*)Alds + (wm + mi * 16 + lrow) * 64 + lq * 16);
#pragma unroll
      for (int ni = 0; ni < 4; ++ni)
        bfr[ni] = *(const s16x8*)((const char*)Blds + (wn + ni * 16 + lrow) * 64 + lq * 16);
#pragma unroll
      for (int mi = 0; mi < 4; ++mi)
#pragma unroll
        for (int ni = 0; ni < 4; ++ni)
          acc[mi][ni] = __builtin_amdgcn_mfma_f32_16x16x32_bf16(af[mi], bfr[ni], acc[mi][ni], 0, 0, 0);
      __syncthreads();
    }
  }
  // epilogue: D row = pos (C/D layout row = lq*4+reg), col = oc (l&15)
#pragma unroll
  for (int mi = 0; mi < 4; ++mi) {
#pragma unroll
    for (int rr = 0; rr < 4; ++rr) {
      const int pos = wm + mi * 16 + lq * 4 + rr;
      const int x = x0 + pos;
      if (x < 224) {
        u16* dst = fuse + ((size_t)(b * 224 + y) * 224 + x) * 128;
#pragma unroll
        for (int ni = 0; ni < 4; ++ni) {
          const int oc = wn + ni * 16 + lrow;
          dst[oc] = f2bf(acc[mi][ni][rr]);
        }
      }
    }
  }
}

// ===========================================================================
// K5: segment-sum of fuse (NHWC bf16) -> global atomics into sums_f.
//     Block = (b, y): one row, 224 px x 64 u32.  Lanes walk channels of one
//     pixel -> all lanes share the label, distinct channels (no same-addr
//     serialization).
// ===========================================================================
__global__ __launch_bounds__(256) void k_segf(const u16* __restrict__ fuse,
                                              const u8* __restrict__ labs,
                                              float* __restrict__ sums_f) {
  const int y = blockIdx.x % 224, b = blockIdx.x / 224;
  __shared__ float acc[NCLS * 129];
  __shared__ u8 ll[224];
  const int t = threadIdx.x;
  for (int e = t; e < NCLS * 129; e += 256) acc[e] = 0.f;
  if (t < 224) ll[t] = labs[((size_t)b * 224 + y) * 224 + t];
  __syncthreads();
  const u32* fb = (const u32*)(fuse + ((size_t)b * 224 + y) * 224 * 128);
  for (int e = t; e < 224 * 64; e += 256) {
    const int c2 = e % 64, px = e / 64;
    const u32 v = fb[(size_t)px * 64 + c2];
    const int lab = ll[px];
    atomicAdd(&acc[lab * 129 + 2 * c2],     __uint_as_float(v << 16));
    atomicAdd(&acc[lab * 129 + 2 * c2 + 1], __uint_as_float(v & 0xffff0000u));
  }
  __syncthreads();
  for (int e = t; e < NCLS * 128; e += 256)
    atomicAdd(&sums_f[b * NCLS * 128 + e], acc[(e / 128) * 129 + (e % 128)]);
}

// ===========================================================================
// K6: gates.  One block per batch, reads tiny sums[b][41][128].
// ===========================================================================
__global__ __launch_bounds__(256) void k_gates(const float* __restrict__ sums,
                                               const int* __restrict__ counts,
                                               const float* __restrict__ w1,
                                               const float* __restrict__ w2,
                                               float* __restrict__ gates) {
  const int b = blockIdx.x;
  __shared__ float att[128];
  __shared__ float hid[8];
  const int t = threadIdx.x;
  if (t < 128) {
    float s1 = 0.f, s2 = 0.f;
    for (int lb = 0; lb < NCLS; ++lb) {
      const float cnt = (float)counts[b * NCLS + lb];
      const float m = sums[(size_t)b * NCLS * 128 + lb * 128 + t] / fmaxf(cnt, 1.f);
      s1 += m; s2 += m * m;
    }
    att[t] = s1 / fmaxf(sqrtf(s2), 1e-12f);
  }
  __syncthreads();
  if (t < 8) {
    float h = 0.f;
    for (int c = 0; c < 128; ++c) h += att[c] * w1[t * 128 + c];
    hid[t] = fmaxf(h, 0.f);
  }
  __syncthreads();
  if (t < 128) {
    float o = 0.f;
    for (int j = 0; j < 8; ++j) o += hid[j] * w2[t * 8 + j];
    gates[b * 128 + t] = 1.f / (1.f + expf(-o));
  }
}

// ===========================================================================
// K7: out(NCHW f32) = fuse(NHWC bf16)*gate_f + d(NCHW)*gate_d
//     Block = (b,y); LDS transpose of fuse row back to channel-major.
// ===========================================================================
__global__ __launch_bounds__(256) void k_out(const u16* __restrict__ fuse,
                                             const float* __restrict__ d,
                                             const float* __restrict__ gates,
                                             float* __restrict__ out) {
  const int y = blockIdx.x % 224, b = blockIdx.x / 224;
  __shared__ float flds[224 * 33];
  __shared__ float gf[128], gd[128];
  const int t = threadIdx.x;
  if (t < 128) gd[t] = gates[b * 128 + t];
  else         gf[t - 128] = gates[512 + b * 128 + (t - 128)];
  const u32* frow = (const u32*)fuse + ((size_t)b * 224 + y) * 224 * 64;
  const float* db = d + (size_t)b * 128 * 50176 + y * 224;
  float* ob = out + (size_t)b * 128 * 50176 + y * 224;
  for (int c0 = 0; c0 < 128; c0 += 32) {
    __syncthreads();
    for (int e = t; e < 224 * 16; e += 256) {
      const int px = e / 16, q = e % 16;
      const u32 v = frow[(size_t)px * 64 + (c0 >> 1) + q];
      flds[px * 33 + 2 * q]     = __uint_as_float(v << 16);
      flds[px * 33 + 2 * q + 1] = __uint_as_float(v & 0xffff0000u);
    }
    __syncthreads();
    for (int e = t; e < 32 * 224; e += 256) {
      const int cc = e / 224, x = e % 224, c = c0 + cc;
      ob[(size_t)c * 50176 + x] = flds[x * 33 + cc] * gf[c] + db[(size_t)c * 50176 + x] * gd[c];
    }
  }
}

// ===========================================================================
extern "C" void kernel_launch(void* const* d_in, const int* in_sizes, int n_in,
                              void* d_out, int out_size, void* d_ws, size_t ws_size,
                              hipStream_t stream) {
  const float* r     = (const float*)d_in[0];
  const float* d     = (const float*)d_in[1];
  const int*   label = (const int*)d_in[2];
  const float* wf    = (const float*)d_in[3];
  const float* w1d   = (const float*)d_in[4];
  const float* w2d   = (const float*)d_in[5];
  const float* w1f   = (const float*)d_in[6];
  const float* w2f   = (const float*)d_in[7];
  float* out = (float*)d_out;

  char* ws = (char*)d_ws;
  size_t off = 0;
  auto carve = [&](size_t bytes) -> char* {
    char* p = ws + off;
    off = (off + bytes + 511) & ~(size_t)511;
    return p;
  };
  u16* X       = (u16*)carve((size_t)4 * 226 * 226 * 256 * 2 + 65536);  // padded NHWC + OOB pad
  u16* Wt      = (u16*)carve((size_t)9 * 128 * 256 * 2);
  u16* fuseb   = (u16*)carve((size_t)4 * 224 * 224 * 128 * 2);
  u8*  labs    = (u8*) carve((size_t)4 * 224 * 224);
  int* counts  = (int*)carve(4 * NCLS * sizeof(int));
  float* sumsd = (float*)carve((size_t)4 * NCLS * 128 * 4);
  float* sumsf = (float*)carve((size_t)4 * NCLS * 128 * 4);
  float* gates = (float*)carve(1024 * sizeof(float));

  hipMemsetAsync(counts, 0, 4 * NCLS * sizeof(int), stream);
  hipMemsetAsync(sumsd, 0, (size_t)4 * NCLS * 128 * 4, stream);
  hipMemsetAsync(sumsf, 0, (size_t)4 * NCLS * 128 * 4, stream);
  k_wprep <<<(9 * 128 * 256 + 255) / 256, 256, 0, stream>>>(wf, Wt);
  k_labels<<<4 * 224, 256, 0, stream>>>(label, labs, counts);
  k_prep  <<<4 * 226, 256, 0, stream>>>(r, d, labs, X, sumsd);
  k_conv  <<<1792, 256, 0, stream>>>(X, Wt, fuseb);
  k_segf  <<<4 * 224, 256, 0, stream>>>(fuseb, labs, sumsf);
  k_gates <<<4, 256, 0, stream>>>(sumsd, counts, w1d, w2d, gates);        // gates[0..511]   = d-module
  k_gates <<<4, 256, 0, stream>>>(sumsf, counts, w1f, w2f, gates + 512);  // gates[512..1023]= fuse-module
  k_out   <<<4 * 224, 256, 0, stream>>>(fuseb, d, gates, out);
}